// Round 2
// baseline (607.463 us; speedup 1.0000x reference)
//
#include <hip/hip_runtime.h>
#include <stdint.h>

#define N_NODES 50000
#define D 128
#define N_EDGES 800000

// ---------------- threefry2x32-20, key = (0, 42), PARTITIONABLE path ----------------
// JAX >= 0.4.36 defaults jax_threefry_partitionable=True:
//   counter = 64-bit iota; x0 = hi(counter)=0, x1 = lo(counter)=idx
//   bits = out0 ^ out1
__device__ __forceinline__ unsigned rotl32(unsigned x, int r){
  return (x << r) | (x >> (32 - r));
}

__device__ __forceinline__ float dropout_factor(unsigned idx){
  unsigned x0 = 0u, x1 = idx;
  const unsigned ks0 = 0u;
  const unsigned ks1 = 42u;
  const unsigned ks2 = 0x1BD11BDAu ^ 0u ^ 42u;
  x0 += ks0; x1 += ks1;
  #define TFR(r) { x0 += x1; x1 = rotl32(x1,(r)); x1 ^= x0; }
  TFR(13) TFR(15) TFR(26) TFR(6)   x0 += ks1; x1 += ks2 + 1u;
  TFR(17) TFR(29) TFR(16) TFR(24)  x0 += ks2; x1 += ks0 + 2u;
  TFR(13) TFR(15) TFR(26) TFR(6)   x0 += ks0; x1 += ks1 + 3u;
  TFR(17) TFR(29) TFR(16) TFR(24)  x0 += ks1; x1 += ks2 + 4u;
  TFR(13) TFR(15) TFR(26) TFR(6)   x0 += ks2; x1 += ks0 + 5u;
  #undef TFR
  unsigned bits = x0 ^ x1;
  float u = __uint_as_float(0x3F800000u | (bits >> 9)) - 1.0f;   // [0,1)
  return (u < 0.8f) ? 1.25f : 0.0f;   // keep -> /0.8 ; drop -> 0
}

// ---------------- edge dtype probe: int64 vs int32 ----------------
// int64 edge values < 50000 => high word of every element is 0.
__global__ void detect_kernel(const void* __restrict__ ei, int* __restrict__ flag){
  __shared__ int nz;
  if (threadIdx.x == 0) nz = 0;
  __syncthreads();
  const int* p = (const int*)ei;
  int local = 0;
  for (int i = threadIdx.x; i < 1024; i += 256)
    if (p[2 * i + 1] != 0) local = 1;
  if (local) atomicAdd(&nz, 1);
  __syncthreads();
  if (threadIdx.x == 0) *flag = (nz == 0) ? 1 : 0;   // 1 => int64 layout
}

__device__ __forceinline__ int edge_val(const void* __restrict__ ei, int is64,
                                        int which, int e){
  if (is64) return (int)((const long long*)ei)[(size_t)which * N_EDGES + e];
  return ((const int*)ei)[(size_t)which * N_EDGES + e];
}

// ---------------- CSR construction ----------------
__global__ void hist_kernel(const void* __restrict__ ei, const int* __restrict__ flag,
                            int* __restrict__ hist){
  int e = blockIdx.x * blockDim.x + threadIdx.x;
  int is64 = *flag;
  if (e < N_EDGES) atomicAdd(&hist[edge_val(ei, is64, 1, e)], 1);
}

__global__ __launch_bounds__(256) void scan_kernel(const int* __restrict__ hist,
                                                   int* __restrict__ rowptr,
                                                   int* __restrict__ fill){
  __shared__ int sums[256];
  const int t = threadIdx.x;
  const int CH = (N_NODES + 255) / 256;   // 196
  int begin = t * CH;
  int end = begin + CH; if (end > N_NODES) end = N_NODES;
  int s = 0;
  for (int i = begin; i < end; ++i) s += hist[i];
  sums[t] = s;
  __syncthreads();
  for (int off = 1; off < 256; off <<= 1){
    int v = (t >= off) ? sums[t - off] : 0;
    __syncthreads();
    sums[t] += v;
    __syncthreads();
  }
  int running = (t == 0) ? 0 : sums[t - 1];
  for (int i = begin; i < end; ++i){
    rowptr[i] = running;
    fill[i]   = running;
    running  += hist[i];
  }
  if (t == 255) rowptr[N_NODES] = running;   // = N_EDGES
}

__global__ void scatter_kernel(const void* __restrict__ ei, const int* __restrict__ flag,
                               int* __restrict__ fill, int* __restrict__ csr){
  int e = blockIdx.x * blockDim.x + threadIdx.x;
  int is64 = *flag;
  if (e < N_EDGES){
    int d = edge_val(ei, is64, 1, e);
    int s = edge_val(ei, is64, 0, e);
    int pos = atomicAdd(&fill[d], 1);
    csr[pos] = s;
  }
}

// ---------------- segment mean: one wave per node, lane holds 2 features ----------------
__global__ __launch_bounds__(256) void agg_mean_kernel(
    const float* __restrict__ X, const int* __restrict__ rowptr,
    const int* __restrict__ csr, float* __restrict__ out)
{
  int node = blockIdx.x * 4 + (threadIdx.x >> 6);
  int lane = threadIdx.x & 63;
  if (node >= N_NODES) return;
  int e0 = rowptr[node], e1 = rowptr[node + 1];
  float ax = 0.f, ay = 0.f;
  for (int e = e0; e < e1; ++e){
    int s = csr[e];
    float2 v = *(const float2*)(X + (size_t)s * D + lane * 2);
    ax += v.x; ay += v.y;
  }
  float cnt = fmaxf((float)(e1 - e0), 1.0f);
  float inv = 1.0f / cnt;
  float2 o; o.x = ax * inv; o.y = ay * inv;
  *(float2*)(out + (size_t)node * D + lane * 2) = o;
}

// ---------------- dual GEMM: out = A1@Wl^T + A2@Wr^T + b (+relu+dropout) ----------------
__global__ __launch_bounds__(256) void gemm_dual(
    const float* __restrict__ A1, const float* __restrict__ A2,
    const float* __restrict__ Wl, const float* __restrict__ Wr,
    const float* __restrict__ bias, float* __restrict__ out, int do_relu_drop)
{
  __shared__ float Al[64][36];    // +4 pad: 16B-aligned b128 reads over k
  __shared__ float Wt[32][129];   // transposed W tile [k][c], +1 pad
  const int t  = threadIdx.x;
  const int tr = t >> 5;          // 0..7
  const int tc = t & 31;          // 0..31
  const int row0 = blockIdx.x * 64;
  float acc[8][4];
  #pragma unroll
  for (int i = 0; i < 8; ++i)
    #pragma unroll
    for (int j = 0; j < 4; ++j) acc[i][j] = 0.0f;

  for (int phase = 0; phase < 2; ++phase){
    const float* __restrict__ A = phase ? A2 : A1;
    const float* __restrict__ W = phase ? Wr : Wl;
    for (int kt = 0; kt < 128; kt += 32){
      #pragma unroll
      for (int u = 0; u < 2; ++u){
        int idx = t + u * 256;
        int r = idx >> 3, kg = idx & 7;
        int gr = row0 + r; if (gr > N_NODES - 1) gr = N_NODES - 1;  // clamp, masked at store
        float4 v = *(const float4*)(A + (size_t)gr * D + kt + kg * 4);
        *(float4*)&Al[r][kg * 4] = v;
      }
      #pragma unroll
      for (int m = 0; m < 4; ++m){
        int c  = (t >> 3) + m * 32;
        int kg = t & 7;
        float4 v = *(const float4*)(W + c * D + kt + kg * 4);
        Wt[kg * 4 + 0][c] = v.x; Wt[kg * 4 + 1][c] = v.y;
        Wt[kg * 4 + 2][c] = v.z; Wt[kg * 4 + 3][c] = v.w;
      }
      __syncthreads();
      #pragma unroll
      for (int kk = 0; kk < 32; kk += 4){
        float4 av[8];
        #pragma unroll
        for (int i = 0; i < 8; ++i)
          av[i] = *(const float4*)&Al[tr + i * 8][kk];
        #pragma unroll
        for (int q = 0; q < 4; ++q){
          float w0 = Wt[kk + q][tc];
          float w1 = Wt[kk + q][tc + 32];
          float w2 = Wt[kk + q][tc + 64];
          float w3 = Wt[kk + q][tc + 96];
          #pragma unroll
          for (int i = 0; i < 8; ++i){
            float a = (q == 0) ? av[i].x : (q == 1) ? av[i].y : (q == 2) ? av[i].z : av[i].w;
            acc[i][0] = fmaf(a, w0, acc[i][0]);
            acc[i][1] = fmaf(a, w1, acc[i][1]);
            acc[i][2] = fmaf(a, w2, acc[i][2]);
            acc[i][3] = fmaf(a, w3, acc[i][3]);
          }
        }
      }
      __syncthreads();
    }
  }
  #pragma unroll
  for (int j = 0; j < 4; ++j){
    int c = tc + j * 32;
    float b = bias[c];
    #pragma unroll
    for (int i = 0; i < 8; ++i){
      int r = row0 + tr + i * 8;
      if (r < N_NODES){
        float v = acc[i][j] + b;
        if (do_relu_drop){
          v = fmaxf(v, 0.0f);
          v *= dropout_factor((unsigned)(r * D + c));
        }
        out[(size_t)r * D + c] = v;
      }
    }
  }
}

// ---------------- launch ----------------
extern "C" void kernel_launch(void* const* d_in, const int* in_sizes, int n_in,
                              void* d_out, int out_size, void* d_ws, size_t ws_size,
                              hipStream_t stream)
{
  const float* x   = (const float*)d_in[0];
  const void*  ei  = d_in[1];                 // [2][800000], int32 or int64 (auto-detected)
  const float* W1l = (const float*)d_in[2];
  const float* W1r = (const float*)d_in[3];
  const float* b1  = (const float*)d_in[4];
  const float* W2l = (const float*)d_in[5];
  const float* W2r = (const float*)d_in[6];
  const float* b2  = (const float*)d_in[7];
  float* out = (float*)d_out;

  char* ws = (char*)d_ws;
  float* mean = (float*)ws;                                  // 25.6 MB
  size_t off = (size_t)N_NODES * D * sizeof(float);
  int* hist   = (int*)(ws + off);  off += (size_t)N_NODES * sizeof(int);
  int* rowptr = (int*)(ws + off);  off += (size_t)(N_NODES + 1) * sizeof(int);
  off = (off + 15) & ~(size_t)15;
  int* fill   = (int*)(ws + off);  off += (size_t)N_NODES * sizeof(int);
  int* csr    = (int*)(ws + off);  off += (size_t)N_EDGES * sizeof(int);
  int* flag   = (int*)(ws + off);  off += 16;

  float* h = out;   // layer-1 activations live in d_out (per-block disjoint rows => safe)

  detect_kernel<<<1, 256, 0, stream>>>(ei, flag);

  // CSR build (shared by both layers)
  hipMemsetAsync(hist, 0, (size_t)N_NODES * sizeof(int), stream);
  hist_kernel<<<(N_EDGES + 255) / 256, 256, 0, stream>>>(ei, flag, hist);
  scan_kernel<<<1, 256, 0, stream>>>(hist, rowptr, fill);
  scatter_kernel<<<(N_EDGES + 255) / 256, 256, 0, stream>>>(ei, flag, fill, csr);

  // layer 1
  agg_mean_kernel<<<(N_NODES + 3) / 4, 256, 0, stream>>>(x, rowptr, csr, mean);
  gemm_dual<<<(N_NODES + 63) / 64, 256, 0, stream>>>(mean, x, W1l, W1r, b1, h, 1);

  // layer 2
  agg_mean_kernel<<<(N_NODES + 3) / 4, 256, 0, stream>>>(h, rowptr, csr, mean);
  gemm_dual<<<(N_NODES + 63) / 64, 256, 0, stream>>>(mean, h, W2l, W2r, b2, out, 0);

  (void)in_sizes; (void)n_in; (void)out_size; (void)ws_size;
}

// Round 3
// 501.122 us; speedup vs baseline: 1.2122x; 1.2122x over previous
//
#include <hip/hip_runtime.h>
#include <stdint.h>

#define N_NODES 50000
#define D 128
#define N_EDGES 800000
#define SCAN_BLOCKS ((N_NODES + 255) / 256)   // 196

// ---------------- threefry2x32-20, key = (0, 42), partitionable path ----------------
__device__ __forceinline__ unsigned rotl32(unsigned x, int r){
  return (x << r) | (x >> (32 - r));
}

__device__ __forceinline__ float dropout_factor(unsigned idx){
  unsigned x0 = 0u, x1 = idx;
  const unsigned ks0 = 0u;
  const unsigned ks1 = 42u;
  const unsigned ks2 = 0x1BD11BDAu ^ 0u ^ 42u;
  x0 += ks0; x1 += ks1;
  #define TFR(r) { x0 += x1; x1 = rotl32(x1,(r)); x1 ^= x0; }
  TFR(13) TFR(15) TFR(26) TFR(6)   x0 += ks1; x1 += ks2 + 1u;
  TFR(17) TFR(29) TFR(16) TFR(24)  x0 += ks2; x1 += ks0 + 2u;
  TFR(13) TFR(15) TFR(26) TFR(6)   x0 += ks0; x1 += ks1 + 3u;
  TFR(17) TFR(29) TFR(16) TFR(24)  x0 += ks1; x1 += ks2 + 4u;
  TFR(13) TFR(15) TFR(26) TFR(6)   x0 += ks2; x1 += ks0 + 5u;
  #undef TFR
  unsigned bits = x0 ^ x1;
  float u = __uint_as_float(0x3F800000u | (bits >> 9)) - 1.0f;   // [0,1)
  return (u < 0.8f) ? 1.25f : 0.0f;
}

// ---------------- edge dtype probe: int64 vs int32 ----------------
__global__ void detect_kernel(const void* __restrict__ ei, int* __restrict__ flag){
  __shared__ int nz;
  if (threadIdx.x == 0) nz = 0;
  __syncthreads();
  const int* p = (const int*)ei;
  int local = 0;
  for (int i = threadIdx.x; i < 1024; i += 256)
    if (p[2 * i + 1] != 0) local = 1;
  if (local) atomicAdd(&nz, 1);
  __syncthreads();
  if (threadIdx.x == 0) *flag = (nz == 0) ? 1 : 0;   // 1 => int64 layout
}

__device__ __forceinline__ int edge_val(const void* __restrict__ ei, int is64,
                                        int which, int e){
  if (is64) return (int)((const long long*)ei)[(size_t)which * N_EDGES + e];
  return ((const int*)ei)[(size_t)which * N_EDGES + e];
}

// ---------------- CSR construction ----------------
__global__ void hist_kernel(const void* __restrict__ ei, const int* __restrict__ flag,
                            int* __restrict__ hist){
  int e = blockIdx.x * blockDim.x + threadIdx.x;
  int is64 = *flag;
  if (e < N_EDGES) atomicAdd(&hist[edge_val(ei, is64, 1, e)], 1);
}

// parallel scan, stage A: per-block inclusive scan + block totals
__global__ __launch_bounds__(256) void scanA_kernel(const int* __restrict__ hist,
                                                    int* __restrict__ incl,
                                                    int* __restrict__ partials){
  __shared__ int s[256];
  int t = threadIdx.x;
  int i = blockIdx.x * 256 + t;
  int v = (i < N_NODES) ? hist[i] : 0;
  s[t] = v;
  __syncthreads();
  #pragma unroll
  for (int off = 1; off < 256; off <<= 1){
    int u = (t >= off) ? s[t - off] : 0;
    __syncthreads();
    s[t] += u;
    __syncthreads();
  }
  if (i < N_NODES) incl[i] = s[t];
  if (t == 255) partials[blockIdx.x] = s[255];
}

// stage B: 1-block exclusive scan of 196 partials
__global__ __launch_bounds__(256) void scanB_kernel(int* __restrict__ partials){
  __shared__ int s[256];
  int t = threadIdx.x;
  s[t] = (t < SCAN_BLOCKS) ? partials[t] : 0;
  __syncthreads();
  #pragma unroll
  for (int off = 1; off < 256; off <<= 1){
    int u = (t >= off) ? s[t - off] : 0;
    __syncthreads();
    s[t] += u;
    __syncthreads();
  }
  if (t < SCAN_BLOCKS) partials[t] = (t == 0) ? 0 : s[t - 1];  // exclusive
}

// stage C: rowptr/fill = exclusive scan = incl - hist + block_offset
__global__ __launch_bounds__(256) void scanC_kernel(const int* __restrict__ hist,
                                                    const int* __restrict__ incl,
                                                    const int* __restrict__ partials,
                                                    int* __restrict__ rowptr,
                                                    int* __restrict__ fill){
  int i = blockIdx.x * 256 + threadIdx.x;
  if (i < N_NODES){
    int ex = incl[i] - hist[i] + partials[blockIdx.x];
    rowptr[i] = ex;
    fill[i]   = ex;
  }
  if (i == 0) rowptr[N_NODES] = N_EDGES;
}

__global__ void scatter_kernel(const void* __restrict__ ei, const int* __restrict__ flag,
                               int* __restrict__ fill, int* __restrict__ csr){
  int e = blockIdx.x * blockDim.x + threadIdx.x;
  int is64 = *flag;
  if (e < N_EDGES){
    int d = edge_val(ei, is64, 1, e);
    int s = edge_val(ei, is64, 0, e);
    int pos = atomicAdd(&fill[d], 1);
    csr[pos] = s;
  }
}

// ---------------- segment mean: one wave per node, lane holds 2 features ----------------
__global__ __launch_bounds__(256) void agg_mean_kernel(
    const float* __restrict__ X, const int* __restrict__ rowptr,
    const int* __restrict__ csr, float* __restrict__ out)
{
  int node = blockIdx.x * 4 + (threadIdx.x >> 6);
  int lane = threadIdx.x & 63;
  if (node >= N_NODES) return;
  int e0 = rowptr[node], e1 = rowptr[node + 1];
  float ax = 0.f, ay = 0.f;
  for (int e = e0; e < e1; ++e){
    int s = csr[e];
    float2 v = *(const float2*)(X + (size_t)s * D + lane * 2);
    ax += v.x; ay += v.y;
  }
  float cnt = fmaxf((float)(e1 - e0), 1.0f);
  float inv = 1.0f / cnt;
  float2 o; o.x = ax * inv; o.y = ay * inv;
  *(float2*)(out + (size_t)node * D + lane * 2) = o;
}

// ---------------- dual GEMM: out = A1@Wl^T + A2@Wr^T + b (+relu+dropout) ----------------
__global__ __launch_bounds__(256) void gemm_dual(
    const float* __restrict__ A1, const float* __restrict__ A2,
    const float* __restrict__ Wl, const float* __restrict__ Wr,
    const float* __restrict__ bias, float* __restrict__ out, int do_relu_drop)
{
  __shared__ float Al[64][36];    // +4 pad: 16B-aligned b128 reads over k
  __shared__ float Wt[32][129];   // transposed W tile [k][c], +1 pad
  const int t  = threadIdx.x;
  const int tr = t >> 5;          // 0..7
  const int tc = t & 31;          // 0..31
  const int row0 = blockIdx.x * 64;
  float acc[8][4];
  #pragma unroll
  for (int i = 0; i < 8; ++i)
    #pragma unroll
    for (int j = 0; j < 4; ++j) acc[i][j] = 0.0f;

  for (int phase = 0; phase < 2; ++phase){
    const float* __restrict__ A = phase ? A2 : A1;
    const float* __restrict__ W = phase ? Wr : Wl;
    for (int kt = 0; kt < 128; kt += 32){
      #pragma unroll
      for (int u = 0; u < 2; ++u){
        int idx = t + u * 256;
        int r = idx >> 3, kg = idx & 7;
        int gr = row0 + r; if (gr > N_NODES - 1) gr = N_NODES - 1;  // clamp, masked at store
        float4 v = *(const float4*)(A + (size_t)gr * D + kt + kg * 4);
        *(float4*)&Al[r][kg * 4] = v;
      }
      #pragma unroll
      for (int m = 0; m < 4; ++m){
        int c  = (t >> 3) + m * 32;
        int kg = t & 7;
        float4 v = *(const float4*)(W + c * D + kt + kg * 4);
        Wt[kg * 4 + 0][c] = v.x; Wt[kg * 4 + 1][c] = v.y;
        Wt[kg * 4 + 2][c] = v.z; Wt[kg * 4 + 3][c] = v.w;
      }
      __syncthreads();
      #pragma unroll
      for (int kk = 0; kk < 32; kk += 4){
        float4 av[8];
        #pragma unroll
        for (int i = 0; i < 8; ++i)
          av[i] = *(const float4*)&Al[tr + i * 8][kk];
        #pragma unroll
        for (int q = 0; q < 4; ++q){
          float w0 = Wt[kk + q][tc];
          float w1 = Wt[kk + q][tc + 32];
          float w2 = Wt[kk + q][tc + 64];
          float w3 = Wt[kk + q][tc + 96];
          #pragma unroll
          for (int i = 0; i < 8; ++i){
            float a = (q == 0) ? av[i].x : (q == 1) ? av[i].y : (q == 2) ? av[i].z : av[i].w;
            acc[i][0] = fmaf(a, w0, acc[i][0]);
            acc[i][1] = fmaf(a, w1, acc[i][1]);
            acc[i][2] = fmaf(a, w2, acc[i][2]);
            acc[i][3] = fmaf(a, w3, acc[i][3]);
          }
        }
      }
      __syncthreads();
    }
  }
  #pragma unroll
  for (int j = 0; j < 4; ++j){
    int c = tc + j * 32;
    float b = bias[c];
    #pragma unroll
    for (int i = 0; i < 8; ++i){
      int r = row0 + tr + i * 8;
      if (r < N_NODES){
        float v = acc[i][j] + b;
        if (do_relu_drop){
          v = fmaxf(v, 0.0f);
          v *= dropout_factor((unsigned)(r * D + c));
        }
        out[(size_t)r * D + c] = v;
      }
    }
  }
}

// ---------------- launch ----------------
extern "C" void kernel_launch(void* const* d_in, const int* in_sizes, int n_in,
                              void* d_out, int out_size, void* d_ws, size_t ws_size,
                              hipStream_t stream)
{
  const float* x   = (const float*)d_in[0];
  const void*  ei  = d_in[1];                 // [2][800000], int32 or int64 (auto-detected)
  const float* W1l = (const float*)d_in[2];
  const float* W1r = (const float*)d_in[3];
  const float* b1  = (const float*)d_in[4];
  const float* W2l = (const float*)d_in[5];
  const float* W2r = (const float*)d_in[6];
  const float* b2  = (const float*)d_in[7];
  float* out = (float*)d_out;

  char* ws = (char*)d_ws;
  float* mean = (float*)ws;                                  // 25.6 MB
  size_t off = (size_t)N_NODES * D * sizeof(float);
  int* hist     = (int*)(ws + off);  off += (size_t)N_NODES * sizeof(int);
  int* rowptr   = (int*)(ws + off);  off += (size_t)(N_NODES + 1) * sizeof(int);
  off = (off + 15) & ~(size_t)15;
  int* fill     = (int*)(ws + off);  off += (size_t)N_NODES * sizeof(int);
  int* csr      = (int*)(ws + off);  off += (size_t)N_EDGES * sizeof(int);
  int* incl     = (int*)(ws + off);  off += (size_t)N_NODES * sizeof(int);
  int* partials = (int*)(ws + off);  off += 256 * sizeof(int);
  int* flag     = (int*)(ws + off);  off += 16;

  float* h = out;   // layer-1 activations live in d_out (per-block disjoint rows => safe)

  detect_kernel<<<1, 256, 0, stream>>>(ei, flag);

  // CSR build (shared by both layers)
  hipMemsetAsync(hist, 0, (size_t)N_NODES * sizeof(int), stream);
  hist_kernel<<<(N_EDGES + 255) / 256, 256, 0, stream>>>(ei, flag, hist);
  scanA_kernel<<<SCAN_BLOCKS, 256, 0, stream>>>(hist, incl, partials);
  scanB_kernel<<<1, 256, 0, stream>>>(partials);
  scanC_kernel<<<SCAN_BLOCKS, 256, 0, stream>>>(hist, incl, partials, rowptr, fill);
  scatter_kernel<<<(N_EDGES + 255) / 256, 256, 0, stream>>>(ei, flag, fill, csr);

  // layer 1
  agg_mean_kernel<<<(N_NODES + 3) / 4, 256, 0, stream>>>(x, rowptr, csr, mean);
  gemm_dual<<<(N_NODES + 63) / 64, 256, 0, stream>>>(mean, x, W1l, W1r, b1, h, 1);

  // layer 2
  agg_mean_kernel<<<(N_NODES + 3) / 4, 256, 0, stream>>>(h, rowptr, csr, mean);
  gemm_dual<<<(N_NODES + 63) / 64, 256, 0, stream>>>(mean, h, W2l, W2r, b2, out, 0);

  (void)in_sizes; (void)n_in; (void)out_size; (void)ws_size;
}

// Round 4
// 338.252 us; speedup vs baseline: 1.7959x; 1.4815x over previous
//
#include <hip/hip_runtime.h>
#include <stdint.h>

#define N_NODES 50000
#define D 128
#define N_EDGES 800000
#define SCAN_BLOCKS ((N_NODES + 255) / 256)   // 196

typedef __attribute__((ext_vector_type(8))) short bf16x8;
typedef __attribute__((ext_vector_type(4))) float f32x4;

// ---------------- bf16 helpers (RNE) ----------------
__device__ __forceinline__ unsigned short f2bf(float f){
  unsigned u = __float_as_uint(f);
  u = u + 0x7FFFu + ((u >> 16) & 1u);
  return (unsigned short)(u >> 16);
}
__device__ __forceinline__ float bf2f(unsigned short h){
  return __uint_as_float(((unsigned)h) << 16);
}

// ---------------- threefry2x32-20, key = (0, 42), partitionable path ----------------
__device__ __forceinline__ unsigned rotl32(unsigned x, int r){
  return (x << r) | (x >> (32 - r));
}
__device__ __forceinline__ float dropout_factor(unsigned idx){
  unsigned x0 = 0u, x1 = idx;
  const unsigned ks0 = 0u;
  const unsigned ks1 = 42u;
  const unsigned ks2 = 0x1BD11BDAu ^ 0u ^ 42u;
  x0 += ks0; x1 += ks1;
  #define TFR(r) { x0 += x1; x1 = rotl32(x1,(r)); x1 ^= x0; }
  TFR(13) TFR(15) TFR(26) TFR(6)   x0 += ks1; x1 += ks2 + 1u;
  TFR(17) TFR(29) TFR(16) TFR(24)  x0 += ks2; x1 += ks0 + 2u;
  TFR(13) TFR(15) TFR(26) TFR(6)   x0 += ks0; x1 += ks1 + 3u;
  TFR(17) TFR(29) TFR(16) TFR(24)  x0 += ks1; x1 += ks2 + 4u;
  TFR(13) TFR(15) TFR(26) TFR(6)   x0 += ks2; x1 += ks0 + 5u;
  #undef TFR
  unsigned bits = x0 ^ x1;
  float u = __uint_as_float(0x3F800000u | (bits >> 9)) - 1.0f;   // [0,1)
  return (u < 0.8f) ? 1.25f : 0.0f;
}

// ---------------- edge dtype probe: int64 vs int32 ----------------
__global__ void detect_kernel(const void* __restrict__ ei, int* __restrict__ flag){
  __shared__ int nz;
  if (threadIdx.x == 0) nz = 0;
  __syncthreads();
  const int* p = (const int*)ei;
  int local = 0;
  for (int i = threadIdx.x; i < 1024; i += 256)
    if (p[2 * i + 1] != 0) local = 1;
  if (local) atomicAdd(&nz, 1);
  __syncthreads();
  if (threadIdx.x == 0) *flag = (nz == 0) ? 1 : 0;   // 1 => int64 layout
}

__device__ __forceinline__ int edge_val(const void* __restrict__ ei, int is64,
                                        int which, int e){
  if (is64) return (int)((const long long*)ei)[(size_t)which * N_EDGES + e];
  return ((const int*)ei)[(size_t)which * N_EDGES + e];
}

// ---------------- CSR construction ----------------
__global__ void hist_kernel(const void* __restrict__ ei, const int* __restrict__ flag,
                            int* __restrict__ hist){
  int e = blockIdx.x * blockDim.x + threadIdx.x;
  int is64 = *flag;
  if (e < N_EDGES) atomicAdd(&hist[edge_val(ei, is64, 1, e)], 1);
}

__global__ __launch_bounds__(256) void scanA_kernel(const int* __restrict__ hist,
                                                    int* __restrict__ incl,
                                                    int* __restrict__ partials){
  __shared__ int s[256];
  int t = threadIdx.x;
  int i = blockIdx.x * 256 + t;
  int v = (i < N_NODES) ? hist[i] : 0;
  s[t] = v;
  __syncthreads();
  #pragma unroll
  for (int off = 1; off < 256; off <<= 1){
    int u = (t >= off) ? s[t - off] : 0;
    __syncthreads();
    s[t] += u;
    __syncthreads();
  }
  if (i < N_NODES) incl[i] = s[t];
  if (t == 255) partials[blockIdx.x] = s[255];
}

__global__ __launch_bounds__(256) void scanB_kernel(int* __restrict__ partials){
  __shared__ int s[256];
  int t = threadIdx.x;
  s[t] = (t < SCAN_BLOCKS) ? partials[t] : 0;
  __syncthreads();
  #pragma unroll
  for (int off = 1; off < 256; off <<= 1){
    int u = (t >= off) ? s[t - off] : 0;
    __syncthreads();
    s[t] += u;
    __syncthreads();
  }
  if (t < SCAN_BLOCKS) partials[t] = (t == 0) ? 0 : s[t - 1];  // exclusive
}

__global__ __launch_bounds__(256) void scanC_kernel(const int* __restrict__ hist,
                                                    const int* __restrict__ incl,
                                                    const int* __restrict__ partials,
                                                    int* __restrict__ rowptr,
                                                    int* __restrict__ fill){
  int i = blockIdx.x * 256 + threadIdx.x;
  if (i < N_NODES){
    int ex = incl[i] - hist[i] + partials[blockIdx.x];
    rowptr[i] = ex;
    fill[i]   = ex;
  }
  if (i == 0) rowptr[N_NODES] = N_EDGES;
}

__global__ void scatter_kernel(const void* __restrict__ ei, const int* __restrict__ flag,
                               int* __restrict__ fill, int* __restrict__ csr){
  int e = blockIdx.x * blockDim.x + threadIdx.x;
  int is64 = *flag;
  if (e < N_EDGES){
    int d = edge_val(ei, is64, 1, e);
    int s = edge_val(ei, is64, 0, e);
    int pos = atomicAdd(&fill[d], 1);
    csr[pos] = s;
  }
}

// ---------------- x fp32 -> bf16 into Acat[:,128:256] ----------------
__global__ __launch_bounds__(256) void convert_kernel(const float* __restrict__ x,
                                                      unsigned short* __restrict__ Acat){
  int i = blockIdx.x * 256 + threadIdx.x;
  if (i >= N_NODES * 32) return;
  int r = i >> 5, c4 = (i & 31) * 4;
  float4 v = *(const float4*)(x + (size_t)r * 128 + c4);
  ushort4 o = make_ushort4(f2bf(v.x), f2bf(v.y), f2bf(v.z), f2bf(v.w));
  *(ushort4*)(Acat + (size_t)r * 256 + 128 + c4) = o;
}

// ---------------- pack W_cat[c][k] = [Wl | Wr] in bf16 ----------------
__global__ __launch_bounds__(256) void packw_kernel(const float* __restrict__ Wl,
                                                    const float* __restrict__ Wr,
                                                    unsigned short* __restrict__ Wcat){
  int c = blockIdx.x;         // 0..127
  int k = threadIdx.x;        // 0..255
  float v = (k < 128) ? Wl[c * 128 + k] : Wr[c * 128 + (k - 128)];
  Wcat[c * 256 + k] = f2bf(v);
}

// ---------------- segment mean (bf16 rows): wave/node, 2 edges per iter ----------------
// reads Acat[:,128:256], writes Acat[:,0:128]
__global__ __launch_bounds__(256) void agg_bf16_kernel(
    unsigned short* __restrict__ Acat, const int* __restrict__ rowptr,
    const int* __restrict__ csr)
{
  int node = blockIdx.x * 4 + (threadIdx.x >> 6);
  int lane = threadIdx.x & 63;
  if (node >= N_NODES) return;
  int half = lane >> 5;
  int fl = lane & 31;
  int e0 = rowptr[node], e1 = rowptr[node + 1];
  float s0 = 0.f, s1 = 0.f, s2 = 0.f, s3 = 0.f;
  for (int e = e0; e < e1; e += 2){
    int ee = e + half;
    if (ee < e1){
      int sr = csr[ee];
      ushort4 v = *(const ushort4*)(Acat + (size_t)sr * 256 + 128 + fl * 4);
      s0 += bf2f(v.x); s1 += bf2f(v.y); s2 += bf2f(v.z); s3 += bf2f(v.w);
    }
  }
  s0 += __shfl_xor(s0, 32);
  s1 += __shfl_xor(s1, 32);
  s2 += __shfl_xor(s2, 32);
  s3 += __shfl_xor(s3, 32);
  if (half == 0){
    float inv = 1.0f / fmaxf((float)(e1 - e0), 1.0f);
    ushort4 o = make_ushort4(f2bf(s0 * inv), f2bf(s1 * inv), f2bf(s2 * inv), f2bf(s3 * inv));
    *(ushort4*)(Acat + (size_t)node * 256 + fl * 4) = o;
  }
}

// ---------------- MFMA GEMM: out = Acat @ Wcat^T + b ----------------
// block: 256 thr, tile 64 rows x 128 cols; wave w -> cols [32w, 32w+32)
// mode 1: relu+dropout, bf16 store into out[:,128:256] (out = A2cat, stride 256)
// mode 0: fp32 store to out (stride 128)
__global__ __launch_bounds__(256) void gemm_mfma(
    const unsigned short* __restrict__ Acat, const unsigned short* __restrict__ Wcat,
    const float* __restrict__ bias, void* __restrict__ outp, int mode)
{
  __shared__ __align__(16) char smem[64 * 132 * 4];   // 33792 B; frag area uses first 32 KB
  const int t   = threadIdx.x;
  const int w   = t >> 6;
  const int tl  = t & 63;
  const int m15 = tl & 15;
  const int q   = tl >> 4;
  const int row0 = blockIdx.x * 64;

  // B-frag preload: lane l holds Wcat[c0+ct*16+(l&15)][kc*32 + (l>>4)*8 + j]
  bf16x8 bfr[2][8];
  #pragma unroll
  for (int ct = 0; ct < 2; ++ct){
    int col = w * 32 + ct * 16 + m15;
    #pragma unroll
    for (int kc = 0; kc < 8; ++kc)
      bfr[ct][kc] = *(const bf16x8*)(Wcat + (size_t)col * 256 + kc * 32 + q * 8);
  }

  // A staging: global (fully coalesced 32 KB) -> LDS fragment layout, XOR-swizzled
  #pragma unroll
  for (int u = 0; u < 8; ++u){
    int g   = t + 256 * u;          // 0..2047
    int row = g >> 5, ch = g & 31;  // ch = 16B chunk within row (k/8)
    int kc  = ch >> 2, qq = ch & 3;
    int f   = (row >> 4) * 8 + kc;  // frag id 0..31  (f&7 == kc)
    int slot = (row & 15) + 16 * qq;
    int gr = row0 + row; if (gr > N_NODES - 1) gr = N_NODES - 1;
    int4 v = *(const int4*)((const char*)Acat + (size_t)gr * 512 + ch * 16);
    *(int4*)(smem + (size_t)(f * 64 + (slot ^ kc)) * 16) = v;
  }
  __syncthreads();

  f32x4 acc[4][2];
  #pragma unroll
  for (int rt = 0; rt < 4; ++rt)
    #pragma unroll
    for (int ct = 0; ct < 2; ++ct)
      acc[rt][ct] = (f32x4){0.f, 0.f, 0.f, 0.f};

  #pragma unroll
  for (int kc = 0; kc < 8; ++kc){
    bf16x8 a[4];
    #pragma unroll
    for (int rt = 0; rt < 4; ++rt)
      a[rt] = *(const bf16x8*)(smem + (size_t)((rt * 8 + kc) * 64 + (tl ^ kc)) * 16);
    #pragma unroll
    for (int rt = 0; rt < 4; ++rt)
      #pragma unroll
      for (int ct = 0; ct < 2; ++ct)
        acc[rt][ct] = __builtin_amdgcn_mfma_f32_16x16x32_bf16(a[rt], bfr[ct][kc], acc[rt][ct], 0, 0, 0);
  }
  __syncthreads();

  // scatter C frags to LDS fp32 [64][132]
  float* sf = (float*)smem;
  #pragma unroll
  for (int rt = 0; rt < 4; ++rt)
    #pragma unroll
    for (int ct = 0; ct < 2; ++ct)
      #pragma unroll
      for (int i = 0; i < 4; ++i){
        int row = rt * 16 + q * 4 + i;
        int col = w * 32 + ct * 16 + m15;
        sf[row * 132 + col] = acc[rt][ct][i];
      }
  __syncthreads();

  if (mode == 1){
    unsigned short* hout = (unsigned short*)outp;   // A2cat, row stride 256, write [:,128:]
    #pragma unroll
    for (int v = 0; v < 4; ++v){
      int s = t + 256 * v;            // 0..1023
      int row = s >> 4, c8 = (s & 15) * 8;
      int gr = row0 + row;
      if (gr < N_NODES){
        float4 p0 = *(const float4*)&sf[row * 132 + c8];
        float4 p1 = *(const float4*)&sf[row * 132 + c8 + 4];
        float vals[8] = {p0.x, p0.y, p0.z, p0.w, p1.x, p1.y, p1.z, p1.w};
        unsigned short ob[8];
        #pragma unroll
        for (int j = 0; j < 8; ++j){
          float vv = vals[j] + bias[c8 + j];
          vv = fmaxf(vv, 0.0f);
          vv *= dropout_factor((unsigned)(gr * 128 + c8 + j));
          ob[j] = f2bf(vv);
        }
        int4 o;
        o.x = (unsigned)ob[0] | ((unsigned)ob[1] << 16);
        o.y = (unsigned)ob[2] | ((unsigned)ob[3] << 16);
        o.z = (unsigned)ob[4] | ((unsigned)ob[5] << 16);
        o.w = (unsigned)ob[6] | ((unsigned)ob[7] << 16);
        *(int4*)(hout + (size_t)gr * 256 + 128 + c8) = o;
      }
    }
  } else {
    float* of = (float*)outp;
    #pragma unroll
    for (int v = 0; v < 8; ++v){
      int s = t + 256 * v;            // 0..2047
      int row = s >> 5, c4 = (s & 31) * 4;
      int gr = row0 + row;
      if (gr < N_NODES){
        float4 p = *(const float4*)&sf[row * 132 + c4];
        p.x += bias[c4 + 0]; p.y += bias[c4 + 1];
        p.z += bias[c4 + 2]; p.w += bias[c4 + 3];
        *(float4*)(of + (size_t)gr * 128 + c4) = p;
      }
    }
  }
}

// ---------------- launch ----------------
extern "C" void kernel_launch(void* const* d_in, const int* in_sizes, int n_in,
                              void* d_out, int out_size, void* d_ws, size_t ws_size,
                              hipStream_t stream)
{
  const float* x   = (const float*)d_in[0];
  const void*  ei  = d_in[1];                 // [2][800000], int32 or int64 (auto-detected)
  const float* W1l = (const float*)d_in[2];
  const float* W1r = (const float*)d_in[3];
  const float* b1  = (const float*)d_in[4];
  const float* W2l = (const float*)d_in[5];
  const float* W2r = (const float*)d_in[6];
  const float* b2  = (const float*)d_in[7];

  char* ws = (char*)d_ws;
  unsigned short* A1cat = (unsigned short*)ws;                   // 50000x256 bf16 = 25.6 MB
  size_t off = (size_t)N_NODES * 256 * sizeof(unsigned short);
  int* hist     = (int*)(ws + off);  off += (size_t)N_NODES * sizeof(int);
  int* rowptr   = (int*)(ws + off);  off += (size_t)(N_NODES + 1) * sizeof(int);
  off = (off + 15) & ~(size_t)15;
  int* fill     = (int*)(ws + off);  off += (size_t)N_NODES * sizeof(int);
  int* csr      = (int*)(ws + off);  off += (size_t)N_EDGES * sizeof(int);
  int* incl     = (int*)(ws + off);  off += (size_t)N_NODES * sizeof(int);
  int* partials = (int*)(ws + off);  off += 256 * sizeof(int);
  int* flag     = (int*)(ws + off);  off += 16;
  off = (off + 15) & ~(size_t)15;
  unsigned short* Wcat1 = (unsigned short*)(ws + off); off += 128 * 256 * sizeof(unsigned short);
  unsigned short* Wcat2 = (unsigned short*)(ws + off); off += 128 * 256 * sizeof(unsigned short);

  // d_out (25.6 MB) doubles as A2cat bf16 [50000][256]; gemm2 overwrites it with fp32
  // (each block stages its own rows to LDS before its epilogue writes them -> safe)
  unsigned short* A2cat = (unsigned short*)d_out;

  detect_kernel<<<1, 256, 0, stream>>>(ei, flag);
  hipMemsetAsync(hist, 0, (size_t)N_NODES * sizeof(int), stream);
  hist_kernel<<<(N_EDGES + 255) / 256, 256, 0, stream>>>(ei, flag, hist);
  scanA_kernel<<<SCAN_BLOCKS, 256, 0, stream>>>(hist, incl, partials);
  scanB_kernel<<<1, 256, 0, stream>>>(partials);
  scanC_kernel<<<SCAN_BLOCKS, 256, 0, stream>>>(hist, incl, partials, rowptr, fill);
  scatter_kernel<<<(N_EDGES + 255) / 256, 256, 0, stream>>>(ei, flag, fill, csr);

  convert_kernel<<<(N_NODES * 32 + 255) / 256, 256, 0, stream>>>(x, A1cat);
  packw_kernel<<<128, 256, 0, stream>>>(W1l, W1r, Wcat1);
  packw_kernel<<<128, 256, 0, stream>>>(W2l, W2r, Wcat2);

  // layer 1
  agg_bf16_kernel<<<(N_NODES + 3) / 4, 256, 0, stream>>>(A1cat, rowptr, csr);
  gemm_mfma<<<(N_NODES + 63) / 64, 256, 0, stream>>>(A1cat, Wcat1, b1, (void*)A2cat, 1);

  // layer 2
  agg_bf16_kernel<<<(N_NODES + 3) / 4, 256, 0, stream>>>(A2cat, rowptr, csr);
  gemm_mfma<<<(N_NODES + 63) / 64, 256, 0, stream>>>(A2cat, Wcat2, b2, d_out, 0);

  (void)in_sizes; (void)n_in; (void)out_size; (void)ws_size;
}

// Round 5
// 275.632 us; speedup vs baseline: 2.2039x; 1.2272x over previous
//
#include <hip/hip_runtime.h>
#include <stdint.h>

#define N_NODES 50000
#define D 128
#define N_EDGES 800000
#define SCAN_BLOCKS ((N_NODES + 255) / 256)   // 196

typedef __attribute__((ext_vector_type(8))) short bf16x8;
typedef __attribute__((ext_vector_type(4))) float f32x4;

// ---------------- bf16 helpers (RNE) ----------------
__device__ __forceinline__ unsigned short f2bf(float f){
  unsigned u = __float_as_uint(f);
  u = u + 0x7FFFu + ((u >> 16) & 1u);
  return (unsigned short)(u >> 16);
}
// accumulate two bf16 packed in one word into two fp32 sums
__device__ __forceinline__ void acc2(float& a, float& b, unsigned w){
  a += __uint_as_float(w << 16);
  b += __uint_as_float(w & 0xFFFF0000u);
}

// ---------------- threefry2x32-20, key = (0, 42), partitionable path ----------------
__device__ __forceinline__ unsigned rotl32(unsigned x, int r){
  return (x << r) | (x >> (32 - r));
}
__device__ __forceinline__ float dropout_factor(unsigned idx){
  unsigned x0 = 0u, x1 = idx;
  const unsigned ks0 = 0u;
  const unsigned ks1 = 42u;
  const unsigned ks2 = 0x1BD11BDAu ^ 0u ^ 42u;
  x0 += ks0; x1 += ks1;
  #define TFR(r) { x0 += x1; x1 = rotl32(x1,(r)); x1 ^= x0; }
  TFR(13) TFR(15) TFR(26) TFR(6)   x0 += ks1; x1 += ks2 + 1u;
  TFR(17) TFR(29) TFR(16) TFR(24)  x0 += ks2; x1 += ks0 + 2u;
  TFR(13) TFR(15) TFR(26) TFR(6)   x0 += ks0; x1 += ks1 + 3u;
  TFR(17) TFR(29) TFR(16) TFR(24)  x0 += ks1; x1 += ks2 + 4u;
  TFR(13) TFR(15) TFR(26) TFR(6)   x0 += ks2; x1 += ks0 + 5u;
  #undef TFR
  unsigned bits = x0 ^ x1;
  float u = __uint_as_float(0x3F800000u | (bits >> 9)) - 1.0f;   // [0,1)
  return (u < 0.8f) ? 1.25f : 0.0f;
}

__device__ __forceinline__ int edge_val(const void* __restrict__ ei, int is64,
                                        int which, int e){
  if (is64) return (int)((const long long*)ei)[(size_t)which * N_EDGES + e];
  return ((const int*)ei)[(size_t)which * N_EDGES + e];
}

// ---------------- fused prep: convert x->bf16, pack W1/W2, zero hist, detect dtype ----
// blocks: [0,6250) convert | [6250,6378) packw1 | [6378,6506) packw2
//         [6506,6702) hist=0 | 6702 detect
__global__ __launch_bounds__(256) void prep_kernel(
    const float* __restrict__ x,
    const float* __restrict__ W1l, const float* __restrict__ W1r,
    const float* __restrict__ W2l, const float* __restrict__ W2r,
    unsigned short* __restrict__ A1cat,
    unsigned short* __restrict__ Wcat1, unsigned short* __restrict__ Wcat2,
    int* __restrict__ hist, const void* __restrict__ ei, int* __restrict__ flag)
{
  int b = blockIdx.x, t = threadIdx.x;
  if (b < 6250){
    int i = b * 256 + t;                       // < 1,600,000 exactly
    int r = i >> 5, c4 = (i & 31) * 4;
    float4 v = *(const float4*)(x + (size_t)r * 128 + c4);
    ushort4 o = make_ushort4(f2bf(v.x), f2bf(v.y), f2bf(v.z), f2bf(v.w));
    *(ushort4*)(A1cat + (size_t)r * 256 + 128 + c4) = o;
  } else if (b < 6506){
    int c = (b < 6378) ? (b - 6250) : (b - 6378);
    const float* Wl = (b < 6378) ? W1l : W2l;
    const float* Wr = (b < 6378) ? W1r : W2r;
    unsigned short* Wc = (b < 6378) ? Wcat1 : Wcat2;
    float v = (t < 128) ? Wl[c * 128 + t] : Wr[c * 128 + (t - 128)];
    Wc[c * 256 + t] = f2bf(v);
  } else if (b < 6702){
    int i = (b - 6506) * 256 + t;
    if (i < N_NODES) hist[i] = 0;
  } else {
    __shared__ int nz;
    if (t == 0) nz = 0;
    __syncthreads();
    const int* p = (const int*)ei;
    int local = 0;
    for (int i = t; i < 1024; i += 256)
      if (p[2 * i + 1] != 0) local = 1;
    if (local) atomicAdd(&nz, 1);
    __syncthreads();
    if (t == 0) *flag = (nz == 0) ? 1 : 0;     // 1 => int64 layout
  }
}

// ---------------- CSR construction (2 edges / thread) ----------------
__global__ __launch_bounds__(256) void hist_kernel(const void* __restrict__ ei,
                                                   const int* __restrict__ flag,
                                                   int* __restrict__ hist){
  int e2 = (blockIdx.x * 256 + threadIdx.x) * 2;
  if (e2 >= N_EDGES) return;
  int d0, d1;
  if (*flag){
    int4 v = *(const int4*)((const long long*)ei + N_EDGES + e2);
    d0 = v.x; d1 = v.z;
  } else {
    int2 v = *(const int2*)((const int*)ei + N_EDGES + e2);
    d0 = v.x; d1 = v.y;
  }
  atomicAdd(&hist[d0], 1);
  atomicAdd(&hist[d1], 1);
}

__global__ __launch_bounds__(256) void scanA_kernel(const int* __restrict__ hist,
                                                    int* __restrict__ incl,
                                                    int* __restrict__ partials){
  __shared__ int s[256];
  int t = threadIdx.x;
  int i = blockIdx.x * 256 + t;
  int v = (i < N_NODES) ? hist[i] : 0;
  s[t] = v;
  __syncthreads();
  #pragma unroll
  for (int off = 1; off < 256; off <<= 1){
    int u = (t >= off) ? s[t - off] : 0;
    __syncthreads();
    s[t] += u;
    __syncthreads();
  }
  if (i < N_NODES) incl[i] = s[t];
  if (t == 255) partials[blockIdx.x] = s[255];
}

__global__ __launch_bounds__(256) void scanB_kernel(int* __restrict__ partials){
  __shared__ int s[256];
  int t = threadIdx.x;
  s[t] = (t < SCAN_BLOCKS) ? partials[t] : 0;
  __syncthreads();
  #pragma unroll
  for (int off = 1; off < 256; off <<= 1){
    int u = (t >= off) ? s[t - off] : 0;
    __syncthreads();
    s[t] += u;
    __syncthreads();
  }
  if (t < SCAN_BLOCKS) partials[t] = (t == 0) ? 0 : s[t - 1];  // exclusive
}

__global__ __launch_bounds__(256) void scanC_kernel(const int* __restrict__ hist,
                                                    const int* __restrict__ incl,
                                                    const int* __restrict__ partials,
                                                    int* __restrict__ rowptr,
                                                    int* __restrict__ fill){
  int i = blockIdx.x * 256 + threadIdx.x;
  if (i < N_NODES){
    int ex = incl[i] - hist[i] + partials[blockIdx.x];
    rowptr[i] = ex;
    fill[i]   = ex;
  }
  if (i == 0) rowptr[N_NODES] = N_EDGES;
}

__global__ __launch_bounds__(256) void scatter_kernel(const void* __restrict__ ei,
                                                      const int* __restrict__ flag,
                                                      int* __restrict__ fill,
                                                      unsigned short* __restrict__ csr16){
  int e2 = (blockIdx.x * 256 + threadIdx.x) * 2;
  if (e2 >= N_EDGES) return;
  int s0, s1, d0, d1;
  if (*flag){
    int4 vs = *(const int4*)((const long long*)ei + e2);
    int4 vd = *(const int4*)((const long long*)ei + N_EDGES + e2);
    s0 = vs.x; s1 = vs.z; d0 = vd.x; d1 = vd.z;
  } else {
    int2 vs = *(const int2*)((const int*)ei + e2);
    int2 vd = *(const int2*)((const int*)ei + N_EDGES + e2);
    s0 = vs.x; s1 = vs.y; d0 = vd.x; d1 = vd.y;
  }
  int p0 = atomicAdd(&fill[d0], 1);
  csr16[p0] = (unsigned short)s0;
  int p1 = atomicAdd(&fill[d1], 1);
  csr16[p1] = (unsigned short)s1;
}

// ---------------- segment mean v2: wave/node, 4 edges/iter (16-lane group = full row),
// unroll x2 -> 8 rows in flight. reads Acat[:,128:256], writes Acat[:,0:128]
__global__ __launch_bounds__(256) void agg_bf16_kernel(
    unsigned short* __restrict__ Acat, const int* __restrict__ rowptr,
    const unsigned short* __restrict__ csr16)
{
  int node = blockIdx.x * 4 + (threadIdx.x >> 6);
  int lane = threadIdx.x & 63;
  if (node >= N_NODES) return;
  int q  = lane >> 4;       // edge slot 0..3
  int fl = lane & 15;       // 16B feature chunk
  int e0 = rowptr[node], e1 = rowptr[node + 1];
  float s0=0.f,s1=0.f,s2=0.f,s3=0.f,s4=0.f,s5=0.f,s6=0.f,s7=0.f;

  int e = e0;
  for (; e + 8 <= e1; e += 8){
    int ia = csr16[e + q];
    int ib = csr16[e + 4 + q];
    int4 va = *(const int4*)(Acat + (size_t)ia * 256 + 128 + fl * 8);
    int4 vb = *(const int4*)(Acat + (size_t)ib * 256 + 128 + fl * 8);
    acc2(s0, s1, (unsigned)va.x); acc2(s2, s3, (unsigned)va.y);
    acc2(s4, s5, (unsigned)va.z); acc2(s6, s7, (unsigned)va.w);
    acc2(s0, s1, (unsigned)vb.x); acc2(s2, s3, (unsigned)vb.y);
    acc2(s4, s5, (unsigned)vb.z); acc2(s6, s7, (unsigned)vb.w);
  }
  for (; e < e1; e += 4){
    int ee = e + q;
    if (ee < e1){
      int ia = csr16[ee];
      int4 va = *(const int4*)(Acat + (size_t)ia * 256 + 128 + fl * 8);
      acc2(s0, s1, (unsigned)va.x); acc2(s2, s3, (unsigned)va.y);
      acc2(s4, s5, (unsigned)va.z); acc2(s6, s7, (unsigned)va.w);
    }
  }
  // combine the 4 edge-groups (lanes differing in bits 4..5)
  s0 += __shfl_xor(s0, 16); s0 += __shfl_xor(s0, 32);
  s1 += __shfl_xor(s1, 16); s1 += __shfl_xor(s1, 32);
  s2 += __shfl_xor(s2, 16); s2 += __shfl_xor(s2, 32);
  s3 += __shfl_xor(s3, 16); s3 += __shfl_xor(s3, 32);
  s4 += __shfl_xor(s4, 16); s4 += __shfl_xor(s4, 32);
  s5 += __shfl_xor(s5, 16); s5 += __shfl_xor(s5, 32);
  s6 += __shfl_xor(s6, 16); s6 += __shfl_xor(s6, 32);
  s7 += __shfl_xor(s7, 16); s7 += __shfl_xor(s7, 32);
  if (q == 0){
    float inv = 1.0f / fmaxf((float)(e1 - e0), 1.0f);
    unsigned short ob[8] = { f2bf(s0*inv), f2bf(s1*inv), f2bf(s2*inv), f2bf(s3*inv),
                             f2bf(s4*inv), f2bf(s5*inv), f2bf(s6*inv), f2bf(s7*inv) };
    int4 o;
    o.x = (unsigned)ob[0] | ((unsigned)ob[1] << 16);
    o.y = (unsigned)ob[2] | ((unsigned)ob[3] << 16);
    o.z = (unsigned)ob[4] | ((unsigned)ob[5] << 16);
    o.w = (unsigned)ob[6] | ((unsigned)ob[7] << 16);
    *(int4*)(Acat + (size_t)node * 256 + fl * 8) = o;
  }
}

// ---------------- MFMA GEMM: out = Acat @ Wcat^T + b ----------------
__global__ __launch_bounds__(256) void gemm_mfma(
    const unsigned short* __restrict__ Acat, const unsigned short* __restrict__ Wcat,
    const float* __restrict__ bias, void* __restrict__ outp, int mode)
{
  __shared__ __align__(16) char smem[64 * 132 * 4];
  const int t   = threadIdx.x;
  const int w   = t >> 6;
  const int tl  = t & 63;
  const int m15 = tl & 15;
  const int q   = tl >> 4;
  const int row0 = blockIdx.x * 64;

  bf16x8 bfr[2][8];
  #pragma unroll
  for (int ct = 0; ct < 2; ++ct){
    int col = w * 32 + ct * 16 + m15;
    #pragma unroll
    for (int kc = 0; kc < 8; ++kc)
      bfr[ct][kc] = *(const bf16x8*)(Wcat + (size_t)col * 256 + kc * 32 + q * 8);
  }

  #pragma unroll
  for (int u = 0; u < 8; ++u){
    int g   = t + 256 * u;
    int row = g >> 5, ch = g & 31;
    int kc  = ch >> 2, qq = ch & 3;
    int f   = (row >> 4) * 8 + kc;
    int slot = (row & 15) + 16 * qq;
    int gr = row0 + row; if (gr > N_NODES - 1) gr = N_NODES - 1;
    int4 v = *(const int4*)((const char*)Acat + (size_t)gr * 512 + ch * 16);
    *(int4*)(smem + (size_t)(f * 64 + (slot ^ kc)) * 16) = v;
  }
  __syncthreads();

  f32x4 acc[4][2];
  #pragma unroll
  for (int rt = 0; rt < 4; ++rt)
    #pragma unroll
    for (int ct = 0; ct < 2; ++ct)
      acc[rt][ct] = (f32x4){0.f, 0.f, 0.f, 0.f};

  #pragma unroll
  for (int kc = 0; kc < 8; ++kc){
    bf16x8 a[4];
    #pragma unroll
    for (int rt = 0; rt < 4; ++rt)
      a[rt] = *(const bf16x8*)(smem + (size_t)((rt * 8 + kc) * 64 + (tl ^ kc)) * 16);
    #pragma unroll
    for (int rt = 0; rt < 4; ++rt)
      #pragma unroll
      for (int ct = 0; ct < 2; ++ct)
        acc[rt][ct] = __builtin_amdgcn_mfma_f32_16x16x32_bf16(a[rt], bfr[ct][kc], acc[rt][ct], 0, 0, 0);
  }
  __syncthreads();

  float* sf = (float*)smem;
  #pragma unroll
  for (int rt = 0; rt < 4; ++rt)
    #pragma unroll
    for (int ct = 0; ct < 2; ++ct)
      #pragma unroll
      for (int i = 0; i < 4; ++i){
        int row = rt * 16 + q * 4 + i;
        int col = w * 32 + ct * 16 + m15;
        sf[row * 132 + col] = acc[rt][ct][i];
      }
  __syncthreads();

  if (mode == 1){
    unsigned short* hout = (unsigned short*)outp;
    #pragma unroll
    for (int v = 0; v < 4; ++v){
      int s = t + 256 * v;
      int row = s >> 4, c8 = (s & 15) * 8;
      int gr = row0 + row;
      if (gr < N_NODES){
        float4 p0 = *(const float4*)&sf[row * 132 + c8];
        float4 p1 = *(const float4*)&sf[row * 132 + c8 + 4];
        float vals[8] = {p0.x, p0.y, p0.z, p0.w, p1.x, p1.y, p1.z, p1.w};
        unsigned short ob[8];
        #pragma unroll
        for (int j = 0; j < 8; ++j){
          float vv = vals[j] + bias[c8 + j];
          vv = fmaxf(vv, 0.0f);
          vv *= dropout_factor((unsigned)(gr * 128 + c8 + j));
          ob[j] = f2bf(vv);
        }
        int4 o;
        o.x = (unsigned)ob[0] | ((unsigned)ob[1] << 16);
        o.y = (unsigned)ob[2] | ((unsigned)ob[3] << 16);
        o.z = (unsigned)ob[4] | ((unsigned)ob[5] << 16);
        o.w = (unsigned)ob[6] | ((unsigned)ob[7] << 16);
        *(int4*)(hout + (size_t)gr * 256 + 128 + c8) = o;
      }
    }
  } else {
    float* of = (float*)outp;
    #pragma unroll
    for (int v = 0; v < 8; ++v){
      int s = t + 256 * v;
      int row = s >> 5, c4 = (s & 31) * 4;
      int gr = row0 + row;
      if (gr < N_NODES){
        float4 p = *(const float4*)&sf[row * 132 + c4];
        p.x += bias[c4 + 0]; p.y += bias[c4 + 1];
        p.z += bias[c4 + 2]; p.w += bias[c4 + 3];
        *(float4*)(of + (size_t)gr * 128 + c4) = p;
      }
    }
  }
}

// ---------------- launch ----------------
extern "C" void kernel_launch(void* const* d_in, const int* in_sizes, int n_in,
                              void* d_out, int out_size, void* d_ws, size_t ws_size,
                              hipStream_t stream)
{
  const float* x   = (const float*)d_in[0];
  const void*  ei  = d_in[1];
  const float* W1l = (const float*)d_in[2];
  const float* W1r = (const float*)d_in[3];
  const float* b1  = (const float*)d_in[4];
  const float* W2l = (const float*)d_in[5];
  const float* W2r = (const float*)d_in[6];
  const float* b2  = (const float*)d_in[7];

  char* ws = (char*)d_ws;
  unsigned short* A1cat = (unsigned short*)ws;                   // 50000x256 bf16
  size_t off = (size_t)N_NODES * 256 * sizeof(unsigned short);
  int* hist     = (int*)(ws + off);  off += (size_t)N_NODES * sizeof(int);
  int* rowptr   = (int*)(ws + off);  off += (size_t)(N_NODES + 1) * sizeof(int);
  off = (off + 15) & ~(size_t)15;
  int* fill     = (int*)(ws + off);  off += (size_t)N_NODES * sizeof(int);
  unsigned short* csr16 = (unsigned short*)(ws + off); off += (size_t)N_EDGES * sizeof(unsigned short);
  int* incl     = (int*)(ws + off);  off += (size_t)N_NODES * sizeof(int);
  int* partials = (int*)(ws + off);  off += 256 * sizeof(int);
  int* flag     = (int*)(ws + off);  off += 16;
  off = (off + 15) & ~(size_t)15;
  unsigned short* Wcat1 = (unsigned short*)(ws + off); off += 128 * 256 * sizeof(unsigned short);
  unsigned short* Wcat2 = (unsigned short*)(ws + off); off += 128 * 256 * sizeof(unsigned short);

  unsigned short* A2cat = (unsigned short*)d_out;   // d_out doubles as bf16 [50000][256]

  prep_kernel<<<6703, 256, 0, stream>>>(x, W1l, W1r, W2l, W2r, A1cat, Wcat1, Wcat2,
                                        hist, ei, flag);
  hist_kernel<<<(N_EDGES / 2 + 255) / 256, 256, 0, stream>>>(ei, flag, hist);
  scanA_kernel<<<SCAN_BLOCKS, 256, 0, stream>>>(hist, incl, partials);
  scanB_kernel<<<1, 256, 0, stream>>>(partials);
  scanC_kernel<<<SCAN_BLOCKS, 256, 0, stream>>>(hist, incl, partials, rowptr, fill);
  scatter_kernel<<<(N_EDGES / 2 + 255) / 256, 256, 0, stream>>>(ei, flag, fill, csr16);

  agg_bf16_kernel<<<(N_NODES + 3) / 4, 256, 0, stream>>>(A1cat, rowptr, csr16);
  gemm_mfma<<<(N_NODES + 63) / 64, 256, 0, stream>>>(A1cat, Wcat1, b1, (void*)A2cat, 1);
  agg_bf16_kernel<<<(N_NODES + 3) / 4, 256, 0, stream>>>(A2cat, rowptr, csr16);
  gemm_mfma<<<(N_NODES + 63) / 64, 256, 0, stream>>>(A2cat, Wcat2, b2, d_out, 0);

  (void)in_sizes; (void)n_in; (void)out_size; (void)ws_size;
}

// Round 6
// 216.851 us; speedup vs baseline: 2.8013x; 1.2711x over previous
//
#include <hip/hip_runtime.h>
#include <stdint.h>

#define N_NODES 50000
#define D 128
#define N_EDGES 800000
#define NBUCK 196          // ceil(50000/256) dst buckets (dst>>8)
#define BCAP 8192          // per-bucket capacity (mean 4082, 16 sigma safety)
#define EPB 4096           // edges per block in bucket pass

typedef __attribute__((ext_vector_type(8))) short bf16x8;
typedef __attribute__((ext_vector_type(4))) float f32x4;

// ---------------- bf16 helpers (RNE) ----------------
__device__ __forceinline__ unsigned short f2bf(float f){
  unsigned u = __float_as_uint(f);
  u = u + 0x7FFFu + ((u >> 16) & 1u);
  return (unsigned short)(u >> 16);
}
__device__ __forceinline__ void acc2(float& a, float& b, unsigned w){
  a += __uint_as_float(w << 16);
  b += __uint_as_float(w & 0xFFFF0000u);
}

// ---------------- threefry2x32-20, key=(0,42), partitionable ----------------
__device__ __forceinline__ unsigned rotl32(unsigned x, int r){
  return (x << r) | (x >> (32 - r));
}
__device__ __forceinline__ float dropout_factor(unsigned idx){
  unsigned x0 = 0u, x1 = idx;
  const unsigned ks0 = 0u;
  const unsigned ks1 = 42u;
  const unsigned ks2 = 0x1BD11BDAu ^ 0u ^ 42u;
  x0 += ks0; x1 += ks1;
  #define TFR(r) { x0 += x1; x1 = rotl32(x1,(r)); x1 ^= x0; }
  TFR(13) TFR(15) TFR(26) TFR(6)   x0 += ks1; x1 += ks2 + 1u;
  TFR(17) TFR(29) TFR(16) TFR(24)  x0 += ks2; x1 += ks0 + 2u;
  TFR(13) TFR(15) TFR(26) TFR(6)   x0 += ks0; x1 += ks1 + 3u;
  TFR(17) TFR(29) TFR(16) TFR(24)  x0 += ks1; x1 += ks2 + 4u;
  TFR(13) TFR(15) TFR(26) TFR(6)   x0 += ks2; x1 += ks0 + 5u;
  #undef TFR
  unsigned bits = x0 ^ x1;
  float u = __uint_as_float(0x3F800000u | (bits >> 9)) - 1.0f;
  return (u < 0.8f) ? 1.25f : 0.0f;
}

// ---------------- fused prep: convert x->bf16, pack W1/W2, zero gcursor, detect ----
// blocks: [0,6250) convert | [6250,6378) packw1 | [6378,6506) packw2
//         6506 zero gcursor | 6507 detect
__global__ __launch_bounds__(256) void prep_kernel(
    const float* __restrict__ x,
    const float* __restrict__ W1l, const float* __restrict__ W1r,
    const float* __restrict__ W2l, const float* __restrict__ W2r,
    unsigned short* __restrict__ A1cat,
    unsigned short* __restrict__ Wcat1, unsigned short* __restrict__ Wcat2,
    int* __restrict__ gcursor, const void* __restrict__ ei, int* __restrict__ flag)
{
  int b = blockIdx.x, t = threadIdx.x;
  if (b < 6250){
    int i = b * 256 + t;
    int r = i >> 5, c4 = (i & 31) * 4;
    float4 v = *(const float4*)(x + (size_t)r * 128 + c4);
    ushort4 o = make_ushort4(f2bf(v.x), f2bf(v.y), f2bf(v.z), f2bf(v.w));
    *(ushort4*)(A1cat + (size_t)r * 256 + 128 + c4) = o;
  } else if (b < 6506){
    int c = (b < 6378) ? (b - 6250) : (b - 6378);
    const float* Wl = (b < 6378) ? W1l : W2l;
    const float* Wr = (b < 6378) ? W1r : W2r;
    unsigned short* Wc = (b < 6378) ? Wcat1 : Wcat2;
    float v = (t < 128) ? Wl[c * 128 + t] : Wr[c * 128 + (t - 128)];
    Wc[c * 256 + t] = f2bf(v);
  } else if (b == 6506){
    if (t < NBUCK) gcursor[t] = 0;
  } else {
    __shared__ int nz;
    if (t == 0) nz = 0;
    __syncthreads();
    const int* p = (const int*)ei;
    int local = 0;
    for (int i = t; i < 1024; i += 256)
      if (p[2 * i + 1] != 0) local = 1;
    if (local) atomicAdd(&nz, 1);
    __syncthreads();
    if (t == 0) *flag = (nz == 0) ? 1 : 0;     // 1 => int64 layout
  }
}

// ---------------- pass B: bucket edges by dst>>8, LDS-rank append ----------------
__global__ __launch_bounds__(256) void bucket_kernel(const void* __restrict__ ei,
                                                     const int* __restrict__ flag,
                                                     int* __restrict__ gcursor,
                                                     int* __restrict__ buck){
  __shared__ int hist[NBUCK];
  __shared__ int baseoff[NBUCK];
  const int t = threadIdx.x;
  const int base = blockIdx.x * EPB;
  for (int i = t; i < NBUCK; i += 256) hist[i] = 0;
  __syncthreads();

  int pk[16], bk[16], rk[16];
  #pragma unroll
  for (int j = 0; j < 16; ++j) bk[j] = -1;

  if (*flag){
    const long long* p = (const long long*)ei;
    #pragma unroll
    for (int k = 0; k < 8; ++k){
      int e = base + (k * 256 + t) * 2;
      if (e < N_EDGES){
        int4 vs = *(const int4*)(p + e);
        int4 vd = *(const int4*)(p + N_EDGES + e);
        int ss0 = vs.x, ss1 = vs.z, dd0 = vd.x, dd1 = vd.z;
        int j0 = k * 2, j1 = k * 2 + 1;
        bk[j0] = dd0 >> 8; pk[j0] = (ss0 << 8) | (dd0 & 255);
        rk[j0] = atomicAdd(&hist[bk[j0]], 1);
        bk[j1] = dd1 >> 8; pk[j1] = (ss1 << 8) | (dd1 & 255);
        rk[j1] = atomicAdd(&hist[bk[j1]], 1);
      }
    }
  } else {
    const int* p = (const int*)ei;
    #pragma unroll
    for (int k = 0; k < 4; ++k){
      int e = base + (k * 256 + t) * 4;
      if (e < N_EDGES){
        int4 vs = *(const int4*)(p + e);
        int4 vd = *(const int4*)(p + N_EDGES + e);
        int ss[4] = {vs.x, vs.y, vs.z, vs.w};
        int dd[4] = {vd.x, vd.y, vd.z, vd.w};
        #pragma unroll
        for (int j = 0; j < 4; ++j){
          int slot = k * 4 + j;
          int d = dd[j];
          bk[slot] = d >> 8;
          pk[slot] = (ss[j] << 8) | (d & 255);
          rk[slot] = atomicAdd(&hist[bk[slot]], 1);
        }
      }
    }
  }
  __syncthreads();
  for (int i = t; i < NBUCK; i += 256){
    int h = hist[i];
    baseoff[i] = h ? atomicAdd(&gcursor[i], h) : 0;
  }
  __syncthreads();
  #pragma unroll
  for (int j = 0; j < 16; ++j){
    if (bk[j] >= 0)
      buck[bk[j] * BCAP + baseoff[bk[j]] + rk[j]] = pk[j];
  }
}

// ---------------- bucket base scan (1 block) ----------------
__global__ __launch_bounds__(256) void bscan_kernel(const int* __restrict__ gcursor,
                                                    int* __restrict__ bucket_base,
                                                    int* __restrict__ rowptr){
  __shared__ int s[256];
  int t = threadIdx.x;
  s[t] = (t < NBUCK) ? gcursor[t] : 0;
  __syncthreads();
  #pragma unroll
  for (int off = 1; off < 256; off <<= 1){
    int u = (t >= off) ? s[t - off] : 0;
    __syncthreads();
    s[t] += u;
    __syncthreads();
  }
  if (t < NBUCK) bucket_base[t] = (t == 0) ? 0 : s[t - 1];
  if (t == 0){ bucket_base[NBUCK] = N_EDGES; rowptr[N_NODES] = N_EDGES; }
}

// ---------------- pass C: per-bucket CSR finalize ----------------
__global__ __launch_bounds__(256) void csr_kernel(const int* __restrict__ gcursor,
                                                  const int* __restrict__ bucket_base,
                                                  const int* __restrict__ buck,
                                                  unsigned short* __restrict__ csr16,
                                                  int* __restrict__ rowptr){
  __shared__ int h[256];
  __shared__ int s[256];
  __shared__ int cur[256];
  const int b = blockIdx.x, t = threadIdx.x;
  const int cntb  = gcursor[b];
  const int gbase = bucket_base[b];
  h[t] = 0;
  __syncthreads();
  for (int i = t; i < cntb; i += 256)
    atomicAdd(&h[buck[b * BCAP + i] & 255], 1);
  __syncthreads();
  s[t] = h[t];
  __syncthreads();
  #pragma unroll
  for (int off = 1; off < 256; off <<= 1){
    int u = (t >= off) ? s[t - off] : 0;
    __syncthreads();
    s[t] += u;
    __syncthreads();
  }
  int excl = s[t] - h[t];
  int node = b * 256 + t;
  if (node < N_NODES) rowptr[node] = gbase + excl;
  cur[t] = gbase + excl;
  __syncthreads();
  for (int i = t; i < cntb; i += 256){
    int pkv = buck[b * BCAP + i];
    int pos = atomicAdd(&cur[pkv & 255], 1);
    csr16[pos] = (unsigned short)(((unsigned)pkv) >> 8);
  }
}

// ---------------- segment mean: wave/node, 4 edges/iter, unroll x2 ----------------
__global__ __launch_bounds__(256) void agg_bf16_kernel(
    unsigned short* __restrict__ Acat, const int* __restrict__ rowptr,
    const unsigned short* __restrict__ csr16)
{
  int node = blockIdx.x * 4 + (threadIdx.x >> 6);
  int lane = threadIdx.x & 63;
  if (node >= N_NODES) return;
  int q  = lane >> 4;
  int fl = lane & 15;
  int e0 = rowptr[node], e1 = rowptr[node + 1];
  float s0=0.f,s1=0.f,s2=0.f,s3=0.f,s4=0.f,s5=0.f,s6=0.f,s7=0.f;

  int e = e0;
  for (; e + 8 <= e1; e += 8){
    int ia = csr16[e + q];
    int ib = csr16[e + 4 + q];
    int4 va = *(const int4*)(Acat + (size_t)ia * 256 + 128 + fl * 8);
    int4 vb = *(const int4*)(Acat + (size_t)ib * 256 + 128 + fl * 8);
    acc2(s0, s1, (unsigned)va.x); acc2(s2, s3, (unsigned)va.y);
    acc2(s4, s5, (unsigned)va.z); acc2(s6, s7, (unsigned)va.w);
    acc2(s0, s1, (unsigned)vb.x); acc2(s2, s3, (unsigned)vb.y);
    acc2(s4, s5, (unsigned)vb.z); acc2(s6, s7, (unsigned)vb.w);
  }
  for (; e < e1; e += 4){
    int ee = e + q;
    if (ee < e1){
      int ia = csr16[ee];
      int4 va = *(const int4*)(Acat + (size_t)ia * 256 + 128 + fl * 8);
      acc2(s0, s1, (unsigned)va.x); acc2(s2, s3, (unsigned)va.y);
      acc2(s4, s5, (unsigned)va.z); acc2(s6, s7, (unsigned)va.w);
    }
  }
  s0 += __shfl_xor(s0, 16); s0 += __shfl_xor(s0, 32);
  s1 += __shfl_xor(s1, 16); s1 += __shfl_xor(s1, 32);
  s2 += __shfl_xor(s2, 16); s2 += __shfl_xor(s2, 32);
  s3 += __shfl_xor(s3, 16); s3 += __shfl_xor(s3, 32);
  s4 += __shfl_xor(s4, 16); s4 += __shfl_xor(s4, 32);
  s5 += __shfl_xor(s5, 16); s5 += __shfl_xor(s5, 32);
  s6 += __shfl_xor(s6, 16); s6 += __shfl_xor(s6, 32);
  s7 += __shfl_xor(s7, 16); s7 += __shfl_xor(s7, 32);
  if (q == 0){
    float inv = 1.0f / fmaxf((float)(e1 - e0), 1.0f);
    unsigned short ob[8] = { f2bf(s0*inv), f2bf(s1*inv), f2bf(s2*inv), f2bf(s3*inv),
                             f2bf(s4*inv), f2bf(s5*inv), f2bf(s6*inv), f2bf(s7*inv) };
    int4 o;
    o.x = (unsigned)ob[0] | ((unsigned)ob[1] << 16);
    o.y = (unsigned)ob[2] | ((unsigned)ob[3] << 16);
    o.z = (unsigned)ob[4] | ((unsigned)ob[5] << 16);
    o.w = (unsigned)ob[6] | ((unsigned)ob[7] << 16);
    *(int4*)(Acat + (size_t)node * 256 + fl * 8) = o;
  }
}

// ---------------- MFMA GEMM: out = Acat @ Wcat^T + b ----------------
__global__ __launch_bounds__(256) void gemm_mfma(
    const unsigned short* __restrict__ Acat, const unsigned short* __restrict__ Wcat,
    const float* __restrict__ bias, void* __restrict__ outp, int mode)
{
  __shared__ __align__(16) char smem[64 * 132 * 4];
  const int t   = threadIdx.x;
  const int w   = t >> 6;
  const int tl  = t & 63;
  const int m15 = tl & 15;
  const int q   = tl >> 4;
  const int row0 = blockIdx.x * 64;

  bf16x8 bfr[2][8];
  #pragma unroll
  for (int ct = 0; ct < 2; ++ct){
    int col = w * 32 + ct * 16 + m15;
    #pragma unroll
    for (int kc = 0; kc < 8; ++kc)
      bfr[ct][kc] = *(const bf16x8*)(Wcat + (size_t)col * 256 + kc * 32 + q * 8);
  }

  #pragma unroll
  for (int u = 0; u < 8; ++u){
    int g   = t + 256 * u;
    int row = g >> 5, ch = g & 31;
    int kc  = ch >> 2, qq = ch & 3;
    int f   = (row >> 4) * 8 + kc;
    int slot = (row & 15) + 16 * qq;
    int gr = row0 + row; if (gr > N_NODES - 1) gr = N_NODES - 1;
    int4 v = *(const int4*)((const char*)Acat + (size_t)gr * 512 + ch * 16);
    *(int4*)(smem + (size_t)(f * 64 + (slot ^ kc)) * 16) = v;
  }
  __syncthreads();

  f32x4 acc[4][2];
  #pragma unroll
  for (int rt = 0; rt < 4; ++rt)
    #pragma unroll
    for (int ct = 0; ct < 2; ++ct)
      acc[rt][ct] = (f32x4){0.f, 0.f, 0.f, 0.f};

  #pragma unroll
  for (int kc = 0; kc < 8; ++kc){
    bf16x8 a[4];
    #pragma unroll
    for (int rt = 0; rt < 4; ++rt)
      a[rt] = *(const bf16x8*)(smem + (size_t)((rt * 8 + kc) * 64 + (tl ^ kc)) * 16);
    #pragma unroll
    for (int rt = 0; rt < 4; ++rt)
      #pragma unroll
      for (int ct = 0; ct < 2; ++ct)
        acc[rt][ct] = __builtin_amdgcn_mfma_f32_16x16x32_bf16(a[rt], bfr[ct][kc], acc[rt][ct], 0, 0, 0);
  }
  __syncthreads();

  float* sf = (float*)smem;
  #pragma unroll
  for (int rt = 0; rt < 4; ++rt)
    #pragma unroll
    for (int ct = 0; ct < 2; ++ct)
      #pragma unroll
      for (int i = 0; i < 4; ++i){
        int row = rt * 16 + q * 4 + i;
        int col = w * 32 + ct * 16 + m15;
        sf[row * 132 + col] = acc[rt][ct][i];
      }
  __syncthreads();

  if (mode == 1){
    unsigned short* hout = (unsigned short*)outp;
    #pragma unroll
    for (int v = 0; v < 4; ++v){
      int s = t + 256 * v;
      int row = s >> 4, c8 = (s & 15) * 8;
      int gr = row0 + row;
      if (gr < N_NODES){
        float4 p0 = *(const float4*)&sf[row * 132 + c8];
        float4 p1 = *(const float4*)&sf[row * 132 + c8 + 4];
        float vals[8] = {p0.x, p0.y, p0.z, p0.w, p1.x, p1.y, p1.z, p1.w};
        unsigned short ob[8];
        #pragma unroll
        for (int j = 0; j < 8; ++j){
          float vv = vals[j] + bias[c8 + j];
          vv = fmaxf(vv, 0.0f);
          vv *= dropout_factor((unsigned)(gr * 128 + c8 + j));
          ob[j] = f2bf(vv);
        }
        int4 o;
        o.x = (unsigned)ob[0] | ((unsigned)ob[1] << 16);
        o.y = (unsigned)ob[2] | ((unsigned)ob[3] << 16);
        o.z = (unsigned)ob[4] | ((unsigned)ob[5] << 16);
        o.w = (unsigned)ob[6] | ((unsigned)ob[7] << 16);
        *(int4*)(hout + (size_t)gr * 256 + 128 + c8) = o;
      }
    }
  } else {
    float* of = (float*)outp;
    #pragma unroll
    for (int v = 0; v < 8; ++v){
      int s = t + 256 * v;
      int row = s >> 5, c4 = (s & 31) * 4;
      int gr = row0 + row;
      if (gr < N_NODES){
        float4 p = *(const float4*)&sf[row * 132 + c4];
        p.x += bias[c4 + 0]; p.y += bias[c4 + 1];
        p.z += bias[c4 + 2]; p.w += bias[c4 + 3];
        *(float4*)(of + (size_t)gr * 128 + c4) = p;
      }
    }
  }
}

// ---------------- launch ----------------
extern "C" void kernel_launch(void* const* d_in, const int* in_sizes, int n_in,
                              void* d_out, int out_size, void* d_ws, size_t ws_size,
                              hipStream_t stream)
{
  const float* x   = (const float*)d_in[0];
  const void*  ei  = d_in[1];
  const float* W1l = (const float*)d_in[2];
  const float* W1r = (const float*)d_in[3];
  const float* b1  = (const float*)d_in[4];
  const float* W2l = (const float*)d_in[5];
  const float* W2r = (const float*)d_in[6];
  const float* b2  = (const float*)d_in[7];

  char* ws = (char*)d_ws;
  unsigned short* A1cat = (unsigned short*)ws;                   // 50000x256 bf16
  size_t off = (size_t)N_NODES * 256 * sizeof(unsigned short);
  int* rowptr      = (int*)(ws + off);  off += (size_t)(N_NODES + 1) * sizeof(int);
  off = (off + 15) & ~(size_t)15;
  unsigned short* csr16 = (unsigned short*)(ws + off); off += (size_t)N_EDGES * sizeof(unsigned short);
  int* gcursor     = (int*)(ws + off);  off += NBUCK * sizeof(int);
  int* bucket_base = (int*)(ws + off);  off += (NBUCK + 1) * sizeof(int);
  int* flag        = (int*)(ws + off);  off += 16;
  off = (off + 15) & ~(size_t)15;
  int* buck        = (int*)(ws + off);  off += (size_t)NBUCK * BCAP * sizeof(int);
  unsigned short* Wcat1 = (unsigned short*)(ws + off); off += 128 * 256 * sizeof(unsigned short);
  unsigned short* Wcat2 = (unsigned short*)(ws + off); off += 128 * 256 * sizeof(unsigned short);

  unsigned short* A2cat = (unsigned short*)d_out;   // d_out doubles as bf16 [50000][256]

  prep_kernel<<<6508, 256, 0, stream>>>(x, W1l, W1r, W2l, W2r, A1cat, Wcat1, Wcat2,
                                        gcursor, ei, flag);
  bucket_kernel<<<(N_EDGES + EPB - 1) / EPB, 256, 0, stream>>>(ei, flag, gcursor, buck);
  bscan_kernel<<<1, 256, 0, stream>>>(gcursor, bucket_base, rowptr);
  csr_kernel<<<NBUCK, 256, 0, stream>>>(gcursor, bucket_base, buck, csr16, rowptr);

  agg_bf16_kernel<<<(N_NODES + 3) / 4, 256, 0, stream>>>(A1cat, rowptr, csr16);
  gemm_mfma<<<(N_NODES + 63) / 64, 256, 0, stream>>>(A1cat, Wcat1, b1, (void*)A2cat, 1);
  agg_bf16_kernel<<<(N_NODES + 3) / 4, 256, 0, stream>>>(A2cat, rowptr, csr16);
  gemm_mfma<<<(N_NODES + 63) / 64, 256, 0, stream>>>(A2cat, Wcat2, b2, d_out, 0);

  (void)in_sizes; (void)n_in; (void)out_size; (void)ws_size;
}